// Round 1
// baseline (111.614 us; speedup 1.0000x reference)
//
#include <hip/hip_runtime.h>
#include <hip/hip_bf16.h>

typedef __attribute__((ext_vector_type(8))) short short8;
typedef __attribute__((ext_vector_type(4))) float f32x4;
typedef __attribute__((ext_vector_type(4))) int   int4v;

#define IN_F  4096
#define OUT_F 11008
#define NTOK  64

// f32 -> bf16 round-to-nearest-even (x path; weight path is exact by construction)
__device__ __forceinline__ short bf16_rne(float f) {
    unsigned u = __builtin_bit_cast(unsigned, f);
    u += 0x7FFFu + ((u >> 16) & 1u);
    return (short)(u >> 16);
}

// Load one K-step (32 k) of weights (2x int4) and x fragments (4 token-groups x 2 float4)
#define LOAD_STEP(BR0, BR1, AR, I) do {                                         \
    const int _off = (I) * 32;                                                  \
    BR0 = *(const int4v*)(wp + _off);                                           \
    BR1 = *(const int4v*)(wp + _off + 4);                                       \
    AR[0][0] = *(const f32x4*)(xp0 + _off); AR[0][1] = *(const f32x4*)(xp0 + _off + 4); \
    AR[1][0] = *(const f32x4*)(xp1 + _off); AR[1][1] = *(const f32x4*)(xp1 + _off + 4); \
    AR[2][0] = *(const f32x4*)(xp2 + _off); AR[2][1] = *(const f32x4*)(xp2 + _off + 4); \
    AR[3][0] = *(const f32x4*)(xp3 + _off); AR[3][1] = *(const f32x4*)(xp3 + _off + 4); \
} while (0)

// Dequant B to bf16 (exact: ints in [-3,123] fit in 8-bit significand), cast A, 4x MFMA
#define COMPUTE_STEP(BR0, BR1, AR) do {                                         \
    short8 bw;                                                                  \
    _Pragma("unroll")                                                           \
    for (int j = 0; j < 4; ++j) {                                               \
        float f0 = (float)(BR0[j] - zp);                                        \
        float f1 = (float)(BR1[j] - zp);                                        \
        bw[j]     = (short)(__builtin_bit_cast(unsigned, f0) >> 16);            \
        bw[j + 4] = (short)(__builtin_bit_cast(unsigned, f1) >> 16);            \
    }                                                                           \
    short8 aw0, aw1, aw2, aw3;                                                  \
    _Pragma("unroll")                                                           \
    for (int j = 0; j < 4; ++j) {                                               \
        aw0[j] = bf16_rne(AR[0][0][j]); aw0[j + 4] = bf16_rne(AR[0][1][j]);     \
        aw1[j] = bf16_rne(AR[1][0][j]); aw1[j + 4] = bf16_rne(AR[1][1][j]);     \
        aw2[j] = bf16_rne(AR[2][0][j]); aw2[j + 4] = bf16_rne(AR[2][1][j]);     \
        aw3[j] = bf16_rne(AR[3][0][j]); aw3[j + 4] = bf16_rne(AR[3][1][j]);     \
    }                                                                           \
    acc0 = __builtin_amdgcn_mfma_f32_16x16x32_bf16(aw0, bw, acc0, 0, 0, 0);     \
    acc1 = __builtin_amdgcn_mfma_f32_16x16x32_bf16(aw1, bw, acc1, 0, 0, 0);     \
    acc2 = __builtin_amdgcn_mfma_f32_16x16x32_bf16(aw2, bw, acc2, 0, 0, 0);     \
    acc3 = __builtin_amdgcn_mfma_f32_16x16x32_bf16(aw3, bw, acc3, 0, 0, 0);     \
} while (0)

__global__ __launch_bounds__(256, 3)
void qlin_mfma(const float* __restrict__ x, const int* __restrict__ w,
               const float* __restrict__ scale_p, const int* __restrict__ zp_p,
               const float* __restrict__ bias, float* __restrict__ out)
{
    const int tid  = threadIdx.x;
    const int lane = tid & 63;
    const int wv   = tid >> 6;      // wave id 0..3 -> K quarter
    const int l15  = lane & 15;     // A: token row / B: out col / D: out col
    const int lg   = lane >> 4;     // k-group (8 k each)
    const int o0   = blockIdx.x * 16;

    const int   zp    = zp_p[0];    // small positive; safe for int32 or int64 storage
    const float scale = scale_p[0];

    const int kbase = wv * 1024 + lg * 8;
    const int*   wp  = w + (size_t)(o0 + l15) * IN_F + kbase;
    const float* xp0 = x + (size_t)(0 * 16 + l15) * IN_F + kbase;
    const float* xp1 = x + (size_t)(1 * 16 + l15) * IN_F + kbase;
    const float* xp2 = x + (size_t)(2 * 16 + l15) * IN_F + kbase;
    const float* xp3 = x + (size_t)(3 * 16 + l15) * IN_F + kbase;

    f32x4 acc0 = {0.f, 0.f, 0.f, 0.f};
    f32x4 acc1 = {0.f, 0.f, 0.f, 0.f};
    f32x4 acc2 = {0.f, 0.f, 0.f, 0.f};
    f32x4 acc3 = {0.f, 0.f, 0.f, 0.f};

    // Register double-buffer (A/B buffers named, never runtime-indexed)
    int4v bA0, bA1, bB0, bB1;
    f32x4 aA[4][2], aB[4][2];

    LOAD_STEP(bA0, bA1, aA, 0);
    for (int i = 0; i < 32; i += 2) {
        LOAD_STEP(bB0, bB1, aB, i + 1);
        COMPUTE_STEP(bA0, bA1, aA);
        if (i + 2 < 32) LOAD_STEP(bA0, bA1, aA, i + 2);
        COMPUTE_STEP(bB0, bB1, aB);
    }

    // Cross-wave K reduction. Pad inner dim to 17 floats: unpadded stride-16
    // would put all 64 lanes of a write on 2 banks (32-way conflict).
    __shared__ float lds[4][64][17];
#pragma unroll
    for (int r = 0; r < 4; ++r) {
        lds[wv][lane][r]      = acc0[r];
        lds[wv][lane][4 + r]  = acc1[r];
        lds[wv][lane][8 + r]  = acc2[r];
        lds[wv][lane][12 + r] = acc3[r];
    }
    __syncthreads();

    {
        const int g  = wv;           // this wave finalizes token-group g
        const int o  = o0 + l15;
        const float bb = bias[o];
#pragma unroll
        for (int r = 0; r < 4; ++r) {
            float s = lds[0][lane][g * 4 + r] + lds[1][lane][g * 4 + r]
                    + lds[2][lane][g * 4 + r] + lds[3][lane][g * 4 + r];
            const int t = g * 16 + lg * 4 + r;   // D row = (lane>>4)*4 + reg
            out[(size_t)t * OUT_F + o] = scale * s + bb;
        }
    }
}

extern "C" void kernel_launch(void* const* d_in, const int* in_sizes, int n_in,
                              void* d_out, int out_size, void* d_ws, size_t ws_size,
                              hipStream_t stream) {
    const float* x     = (const float*)d_in[0];
    const int*   w     = (const int*)d_in[1];
    const float* scale = (const float*)d_in[2];
    const int*   zp    = (const int*)d_in[3];
    const float* bias  = (const float*)d_in[4];
    float*       out   = (float*)d_out;

    qlin_mfma<<<dim3(OUT_F / 16), dim3(256), 0, stream>>>(x, w, scale, zp, bias, out);
}

// Round 2
// 68.662 us; speedup vs baseline: 1.6256x; 1.6256x over previous
//
#include <hip/hip_runtime.h>
#include <hip/hip_bf16.h>

typedef __attribute__((ext_vector_type(8))) short short8;
typedef __attribute__((ext_vector_type(4))) float f32x4;
typedef __attribute__((ext_vector_type(4))) int   int4v;

#define IN_F  4096
#define OUT_F 11008
#define BK    64
#define NIT   (IN_F / BK)   // 64 iterations

// f32 -> bf16 round-to-nearest-even (x path; weight path is exact by construction)
__device__ __forceinline__ short bf16_rne(float f) {
    unsigned u = __builtin_bit_cast(unsigned, f);
    u += 0x7FFFu + ((u >> 16) & 1u);
    return (short)(u >> 16);
}

// async global->LDS, 16B per lane; dest is wave-uniform base + lane*16 (linear)
__device__ __forceinline__ void gld16(const void* g, void* l) {
    __builtin_amdgcn_global_load_lds(
        (const __attribute__((address_space(1))) unsigned int*)g,
        (__attribute__((address_space(3))) unsigned int*)l,
        16, 0, 0);
}

// Stage one BK=64 K-chunk: W tile 16x64 int32 (4KB), X tile 64x64 f32 (16KB).
// Source chunk index is pre-swizzled (c ^ (row&7)) so a linear LDS write +
// swizzled read yields conflict-free ds_read_b128 (rule #21: both-sides).
#define STAGE(B, IT) do {                                                   \
    const int*   _ws = wsrc + (IT) * BK;                                    \
    const float* _xs = xsrc + (IT) * BK;                                    \
    gld16(_ws,             (char*)wt[B] + tid * 16);                        \
    gld16(_xs,             (char*)xt[B] + tid * 16);                        \
    gld16(_xs + 16 * IN_F, (char*)xt[B] + tid * 16 + 4096);                 \
    gld16(_xs + 32 * IN_F, (char*)xt[B] + tid * 16 + 8192);                 \
    gld16(_xs + 48 * IN_F, (char*)xt[B] + tid * 16 + 12288);                \
} while (0)

// One MFMA K-step (32 k) for this wave: read swizzled A/B fragments, dequant, MFMA.
#define KSTEP(BUF, KK) do {                                                 \
    const char* _wb = (const char*)wt[BUF] + l15 * 256;                     \
    const char* _xb = (const char*)xt[BUF] + rowA * 256;                    \
    const int _c0 = (KK) * 8 + lg * 2;                                      \
    int4v _b0 = *(const int4v*)(_wb + (((_c0    ) ^ swz) * 16));            \
    int4v _b1 = *(const int4v*)(_wb + (((_c0 + 1) ^ swz) * 16));            \
    f32x4 _a0 = *(const f32x4*)(_xb + (((_c0    ) ^ swz) * 16));            \
    f32x4 _a1 = *(const f32x4*)(_xb + (((_c0 + 1) ^ swz) * 16));            \
    short8 _bw, _aw;                                                        \
    _Pragma("unroll")                                                       \
    for (int j = 0; j < 4; ++j) {                                           \
        float f0 = (float)(_b0[j] - zp);                                    \
        float f1 = (float)(_b1[j] - zp);                                    \
        _bw[j]     = (short)(__builtin_bit_cast(unsigned, f0) >> 16);       \
        _bw[j + 4] = (short)(__builtin_bit_cast(unsigned, f1) >> 16);       \
        _aw[j]     = bf16_rne(_a0[j]);                                      \
        _aw[j + 4] = bf16_rne(_a1[j]);                                      \
    }                                                                       \
    acc = __builtin_amdgcn_mfma_f32_16x16x32_bf16(_aw, _bw, acc, 0, 0, 0);  \
} while (0)

__global__ __launch_bounds__(256, 4)
void qlin_mfma2(const float* __restrict__ x, const int* __restrict__ w,
                const float* __restrict__ scale_p, const int* __restrict__ zp_p,
                const float* __restrict__ bias, float* __restrict__ out)
{
    __shared__ int   wt[2][16 * BK];   // 2 x 4KB
    __shared__ float xt[2][64 * BK];   // 2 x 16KB   (40KB total -> 4 blocks/CU)

    const int tid  = threadIdx.x;
    const int lane = tid & 63;
    const int wv   = tid >> 6;        // wave 0..3 -> token group
    const int l15  = lane & 15;
    const int lg   = lane >> 4;
    const int o0   = blockIdx.x * 16;

    const int   zp    = zp_p[0];
    const float scale = scale_p[0];

    // Staging source pointers. Thread t owns LDS chunk t (16B): row t>>4, chunk t&15.
    // Pre-swizzle the source chunk: cs = c ^ (row&7). For X rows (t>>4)+16j the
    // swizzle is identical since 16j % 8 == 0.
    const int wr  = tid >> 4;
    const int wc  = tid & 15;
    const int wcs = wc ^ (wr & 7);
    const int*   wsrc = w + (size_t)(o0 + wr) * IN_F + wcs * 4;
    const float* xsrc = x + (size_t)wr * IN_F + wcs * 4;

    // Fragment geometry: A row = token (wv*16 + l15), B row = out col (l15),
    // both at 256B row stride in LDS; swz = row&7 for both.
    const int rowA = wv * 16 + l15;
    const int swz  = l15 & 7;

    f32x4 acc = {0.f, 0.f, 0.f, 0.f};

    STAGE(0, 0);
    asm volatile("s_waitcnt vmcnt(0)" ::: "memory");
    __builtin_amdgcn_s_barrier();

#pragma unroll 2
    for (int it = 0; it < NIT; ++it) {
        const int buf = it & 1;
        if (it + 1 < NIT) STAGE(buf ^ 1, it + 1);  // prefetch overlaps compute below
        KSTEP(buf, 0);
        KSTEP(buf, 1);
        asm volatile("s_waitcnt vmcnt(0)" ::: "memory");
        __builtin_amdgcn_s_barrier();
    }

    // Epilogue: D layout col=lane&15, row=(lane>>4)*4+reg. No cross-wave reduce.
    {
        const int   o  = o0 + l15;
        const float bb = bias[o];
#pragma unroll
        for (int r = 0; r < 4; ++r) {
            const int t = wv * 16 + lg * 4 + r;
            out[(size_t)t * OUT_F + o] = scale * acc[r] + bb;
        }
    }
}

extern "C" void kernel_launch(void* const* d_in, const int* in_sizes, int n_in,
                              void* d_out, int out_size, void* d_ws, size_t ws_size,
                              hipStream_t stream) {
    const float* x     = (const float*)d_in[0];
    const int*   w     = (const int*)d_in[1];
    const float* scale = (const float*)d_in[2];
    const int*   zp    = (const int*)d_in[3];
    const float* bias  = (const float*)d_in[4];
    float*       out   = (float*)d_out;

    qlin_mfma2<<<dim3(OUT_F / 16), dim3(256), 0, stream>>>(x, w, scale, zp, bias, out);
}

// Round 3
// 55.447 us; speedup vs baseline: 2.0130x; 1.2383x over previous
//
#include <hip/hip_runtime.h>
#include <hip/hip_bf16.h>

typedef __attribute__((ext_vector_type(8))) short short8;
typedef __attribute__((ext_vector_type(4))) float f32x4;
typedef __attribute__((ext_vector_type(4))) int   int4v;

#define IN_F  4096
#define OUT_F 11008
#define NTOK  64
#define BK    64
#define NIT   (IN_F / BK)   // 64 K-chunks
#define DEPTH 4             // LDS ring slots, stage-ahead 2, vmcnt(6)

// f32 -> bf16 round-to-nearest-even
__device__ __forceinline__ short bf16_rne(float f) {
    unsigned u = __builtin_bit_cast(unsigned, f);
    u += 0x7FFFu + ((u >> 16) & 1u);
    return (short)(u >> 16);
}

// async global->LDS, 16B/lane; LDS dest is wave-uniform base + lane*16 (linear)
__device__ __forceinline__ void gld16(const void* g, void* l) {
    __builtin_amdgcn_global_load_lds(
        (const __attribute__((address_space(1))) unsigned int*)g,
        (__attribute__((address_space(3))) unsigned int*)l,
        16, 0, 0);
}

// ---------- pre-pass: X f32 -> bf16 row-major [64][4096] in d_ws ----------
__global__ __launch_bounds__(256)
void xcast(const float* __restrict__ x, unsigned short* __restrict__ xb) {
    const int i = (blockIdx.x * 256 + threadIdx.x) * 8;
    f32x4 a = *(const f32x4*)(x + i);
    f32x4 b = *(const f32x4*)(x + i + 4);
    short8 o;
#pragma unroll
    for (int j = 0; j < 4; ++j) { o[j] = bf16_rne(a[j]); o[j + 4] = bf16_rne(b[j]); }
    *(short8*)(xb + i) = o;
}

// ---------- main GEMM ----------
// Stage chunk IT into ring slot IT&3: W 16x64 int32 (4KB, 1 gld/thr),
// X 64x64 bf16 (8KB, 2 gld/thr). Sources pre-swizzled (chunk ^ row&7),
// LDS dest linear (rule #21: swizzle both-sides-or-neither).
#define STAGE(IT) do {                                                        \
    const int _s = (IT) & (DEPTH - 1);                                        \
    gld16(wsrc + (size_t)(IT) * BK,             (char*)wt[_s] + tid * 16);    \
    gld16(xsrc + (size_t)(IT) * BK,             (char*)xt[_s] + tid * 16);    \
    gld16(xsrc + (size_t)(IT) * BK + 32 * IN_F, (char*)xt[_s] + tid * 16 + 4096); \
} while (0)

// One MFMA K-step (32 k): 2 W-reads (b128), 1 A-read (b128), dequant, MFMA.
#define KSTEP(S, KK) do {                                                     \
    const char* _wb = (const char*)wt[S] + l15 * 256;                         \
    const char* _ab = (const char*)xt[S] + (wv * 16 + l15) * 128;             \
    const int _cw = (KK) * 8 + lg * 2;                                        \
    const int _ca = (KK) * 4 + lg;                                            \
    int4v  _b0 = *(const int4v*)(_wb + (((_cw    ) ^ rswz) * 16));            \
    int4v  _b1 = *(const int4v*)(_wb + (((_cw + 1) ^ rswz) * 16));            \
    short8 _aw = *(const short8*)(_ab + ((_ca ^ rswz) * 16));                 \
    short8 _bw;                                                               \
    _Pragma("unroll")                                                         \
    for (int j = 0; j < 4; ++j) {                                             \
        float f0 = (float)(_b0[j] - zp);                                      \
        float f1 = (float)(_b1[j] - zp);                                      \
        _bw[j]     = (short)(__builtin_bit_cast(unsigned, f0) >> 16);         \
        _bw[j + 4] = (short)(__builtin_bit_cast(unsigned, f1) >> 16);         \
    }                                                                         \
    acc = __builtin_amdgcn_mfma_f32_16x16x32_bf16(_aw, _bw, acc, 0, 0, 0);    \
} while (0)

#define WAIT_BAR(N) do {                                                      \
    asm volatile("s_waitcnt vmcnt(" #N ")" ::: "memory");                     \
    __builtin_amdgcn_s_barrier();                                             \
    asm volatile("" ::: "memory");                                            \
} while (0)

__global__ __launch_bounds__(256, 3)
void qlin3(const unsigned short* __restrict__ xb, const int* __restrict__ w,
           const float* __restrict__ scale_p, const int* __restrict__ zp_p,
           const float* __restrict__ bias, float* __restrict__ out)
{
    __shared__ __align__(16) int            wt[DEPTH][16 * BK];  // 4 x 4KB
    __shared__ __align__(16) unsigned short xt[DEPTH][64 * BK];  // 4 x 8KB  (48KB -> 3 blk/CU)

    const int tid  = threadIdx.x;
    const int lane = tid & 63;
    const int wv   = tid >> 6;      // wave -> token group (16 tokens)
    const int l15  = lane & 15;
    const int lg   = lane >> 4;
    const int o0   = blockIdx.x * 16;

    const int   zp    = zp_p[0];
    const float scale = scale_p[0];

    // Staging source pointers (swizzle folded into the global address).
    const int wr = tid >> 4;                  // W row 0..15, 16B-chunk (tid&15)
    const int wc = (tid & 15) ^ (wr & 7);
    const int* wsrc = w + (size_t)(o0 + wr) * IN_F + wc * 4;

    const int xr = tid >> 3;                  // X rows xr and xr+32, chunk (tid&7)
    const int xc = (tid & 7) ^ (xr & 7);
    const unsigned short* xsrc = xb + (size_t)xr * IN_F + xc * 8;

    // Fragment read swizzle: A row = wv*16+l15 (row&7 == l15&7), B row = l15.
    const int rswz = l15 & 7;

    f32x4 acc = {0.f, 0.f, 0.f, 0.f};

    STAGE(0);
    STAGE(1);

#pragma unroll 2
    for (int it = 0; it < NIT - 2; ++it) {
        STAGE(it + 2);               // 3 vmem; up to 9 in flight
        WAIT_BAR(6);                 // chunk `it` landed; it+1/it+2 stay in flight
        const int s = it & (DEPTH - 1);
        KSTEP(s, 0);
        KSTEP(s, 1);
    }
    // Tail: drain progressively, never stalling earlier than needed.
    WAIT_BAR(3);
    KSTEP((NIT - 2) & (DEPTH - 1), 0);
    KSTEP((NIT - 2) & (DEPTH - 1), 1);
    WAIT_BAR(0);
    KSTEP((NIT - 1) & (DEPTH - 1), 0);
    KSTEP((NIT - 1) & (DEPTH - 1), 1);

    // Epilogue: D layout col=lane&15, row=(lane>>4)*4+reg (verified r0/r1).
    {
        const int   o  = o0 + l15;
        const float bb = bias[o];
#pragma unroll
        for (int r = 0; r < 4; ++r) {
            const int t = wv * 16 + lg * 4 + r;
            out[(size_t)t * OUT_F + o] = scale * acc[r] + bb;
        }
    }
}

extern "C" void kernel_launch(void* const* d_in, const int* in_sizes, int n_in,
                              void* d_out, int out_size, void* d_ws, size_t ws_size,
                              hipStream_t stream) {
    const float* x     = (const float*)d_in[0];
    const int*   w     = (const int*)d_in[1];
    const float* scale = (const float*)d_in[2];
    const int*   zp    = (const int*)d_in[3];
    const float* bias  = (const float*)d_in[4];
    float*       out   = (float*)d_out;
    unsigned short* xbf = (unsigned short*)d_ws;   // needs 512 KB of d_ws

    // 64*4096 = 262144 elems, 8/thread, 256 thr -> 128 blocks
    xcast<<<dim3(128), dim3(256), 0, stream>>>(x, xbf);
    qlin3<<<dim3(OUT_F / 16), dim3(256), 0, stream>>>(xbf, w, scale, zp, bias, out);
}